// Round 5
// baseline (671.949 us; speedup 1.0000x reference)
//
#include <hip/hip_runtime.h>

// PositionAwareAttention: S=8192, B=64, D=512, A=256, all fp32 I/O.
// R5: producer/consumer wave specialization. 256 blocks (1/CU), 512 thr.
// Each block: 32 s-tiles of 64 rows, double-buffered 64 KiB fp16 LDS x-tile.
//   waves 0-3 (consumers): wx = x.W^T via f16 MFMA (each wave: 64 rows x
//     64-a-col quarter), B-frags streamed from packed global W (R4 layout).
//   waves 4-7 (producers): stage tile i+1 HBM->f16 LDS while consumers
//     compute tile i. vmcnt is per-wave, so producer waits never stall
//     consumers -> HBM stays saturated through the whole kernel.
// Epilogue per tile: tanh+Wt -> tile softmax partial (m,l) + weighted sum.
// k3 combines 128 tile-partials per b. bt omitted (softmax shift-invariant).

#define S_DIM 8192
#define B_DIM 64
#define D_DIM 512
#define A_DIM 256
#define BM 64
#define NTILES 128
#define TPB 32            // tiles per block
#define NBLK 256          // 64 b x 4 sgrp (1 block/CU)

typedef _Float16 half4 __attribute__((ext_vector_type(4)));
typedef _Float16 half8 __attribute__((ext_vector_type(8)));
typedef float f32x4 __attribute__((ext_vector_type(4)));

// LDS: xs dbuf 2*65536 + red 16384 + scorep 1024 + pbuf 256 + whb_s 1024 + wt_s 1024
#define SMEM_MAIN (131072 + 16384 + 1024 + 256 + 1024 + 1024)

__device__ __forceinline__ float tanh_fast(float x) {
  // tanh(x) = 1 - 2/(exp(2x)+1); exp->inf/0 saturates correctly to +/-1
  float e = __expf(2.0f * x);
  return 1.0f - 2.0f * __builtin_amdgcn_rcpf(e + 1.0f);
}

// Pack Wx (A=256 x K=512 f32) -> fp16 fragment tiles (R4 layout).
// elem (a=ta*16+fr, k=tk*32+fg*8+j) at Wp[(ta*16+tk)*512 + (fg*16+fr)*8 + j]
__global__ void __launch_bounds__(256)
convw_kernel(const float* __restrict__ Wx, _Float16* __restrict__ Wp) {
  const int idx = (blockIdx.x * 256 + threadIdx.x) * 8;
  const int a = idx >> 9;
  const int k = idx & 511;
  f32x4 va = *(const f32x4*)(Wx + idx);
  f32x4 vb = *(const f32x4*)(Wx + idx + 4);
  half8 hx;
#pragma unroll
  for (int i = 0; i < 4; ++i) { hx[i] = (_Float16)va[i]; hx[4 + i] = (_Float16)vb[i]; }
  const int ta = a >> 4, fr = a & 15;
  const int tk = k >> 5, fg = (k >> 3) & 3;
  *(half8*)(Wp + (ta * 16 + tk) * 512 + (fg * 16 + fr) * 8) = hx;
}

__global__ void __launch_bounds__(256)
whb_kernel(const float* __restrict__ h, const float* __restrict__ Wh,
           const float* __restrict__ bx, float* __restrict__ whb) {
  __shared__ float hs[D_DIM];
  const int b = blockIdx.x, tid = threadIdx.x;
  hs[tid] = h[b * D_DIM + tid];
  hs[tid + 256] = h[b * D_DIM + 256 + tid];
  __syncthreads();
  const int g = tid >> 4, i = tid & 15;
  for (int pass = 0; pass < 16; ++pass) {
    const int a = pass * 16 + g;
    const f32x4* wrow = (const f32x4*)(Wh + (size_t)a * D_DIM);
    float dot = 0.f;
#pragma unroll
    for (int k = 0; k < 8; ++k) {
      f32x4 wv = wrow[i + k * 16];
      f32x4 hv = *(const f32x4*)(hs + (i + k * 16) * 4);
      dot += wv[0] * hv[0] + wv[1] * hv[1] + wv[2] * hv[2] + wv[3] * hv[3];
    }
#pragma unroll
    for (int mask = 1; mask < 16; mask <<= 1) dot += __shfl_xor(dot, mask, 64);
    if (i == 0) whb[b * A_DIM + a] = dot + bx[a];
  }
}

// Stage NR rows of x tile t_idx (rows r0..r0+NR) into swizzled f16 LDS.
// Per lane per row: 2 fully-coalesced dwordx4 loads + 2 ds_write_b64.
// Storage: elem (row,c) at row*512 + ((c/8)^(row&7))*8 + c%8 (same as R4).
template <int NR>
__device__ __forceinline__ void stage_rows(_Float16* dst, const float* __restrict__ x,
                                           int t_idx, int b, int r0, int lane) {
#pragma unroll
  for (int rr = 0; rr < NR; ++rr) {
    const int row = r0 + rr;
    const float* rp = x + ((size_t)(t_idx * BM + row) * B_DIM + b) * D_DIM;
    f32x4 v0 = *(const f32x4*)(rp + lane * 4);
    f32x4 v1 = *(const f32x4*)(rp + 256 + lane * 4);
    half4 h0, h1;
#pragma unroll
    for (int j = 0; j < 4; ++j) { h0[j] = (_Float16)v0[j]; h1[j] = (_Float16)v1[j]; }
    const int sl = (((lane >> 1) ^ (row & 7)) << 3) + ((lane & 1) << 2);
    *(half4*)(dst + row * D_DIM + sl) = h0;
    *(half4*)(dst + row * D_DIM + sl + 256) = h1;
  }
}

__global__ void __launch_bounds__(512, 2)
paa_main(const float* __restrict__ x, const _Float16* __restrict__ Wp,
         const float* __restrict__ whb, const float* __restrict__ Wt,
         float* __restrict__ m_arr, float* __restrict__ l_arr,
         float* __restrict__ acc_arr) {
  extern __shared__ char smem[];
  _Float16* xs0 = (_Float16*)smem;                 // [64][512] f16, buf 0
  _Float16* xs1 = (_Float16*)(smem + 65536);       // buf 1
  float* red    = (float*)(smem + 131072);         // [8][512]
  float* scorep = (float*)(smem + 131072 + 16384); // [4][64]
  float* pbuf   = scorep + 256;                    // [64]
  float* whb_s  = pbuf + 64;                       // [256]
  float* wt_s   = whb_s + 256;                     // [256]

  const int tid = threadIdx.x;
  const int lane = tid & 63;
  const int wv = tid >> 6;
  const int b = blockIdx.x >> 2;
  const int sgrp = blockIdx.x & 3;

  if (tid < A_DIM) { whb_s[tid] = whb[b * A_DIM + tid]; wt_s[tid] = Wt[tid]; }

  const int fr = lane & 15, fg = lane >> 4;
  // consumer (wv<4): wave's W quarter, packed+lane-contiguous (R4 layout)
  const _Float16* wpb = Wp + (wv & 3) * (4 * 16 * 512) + lane * 8;

  // prologue: all 8 waves stage tile 0 of this block's range
  stage_rows<8>(xs0, x, sgrp * TPB, b, wv * 8, lane);
  __syncthreads();

  for (int i = 0; i < TPB; ++i) {
    const int t_idx = sgrp * TPB + i;
    _Float16* xcur = (i & 1) ? xs1 : xs0;
    _Float16* xnxt = (i & 1) ? xs0 : xs1;

    if (wv < 4) {
      // ---- consumer: K-loop, no barriers; B-frags from global (L1/L2)
      f32x4 acc[4][4];
#pragma unroll
      for (int mf = 0; mf < 4; ++mf)
#pragma unroll
        for (int nf = 0; nf < 4; ++nf) acc[mf][nf] = (f32x4){0.f, 0.f, 0.f, 0.f};
#pragma unroll
      for (int tk = 0; tk < 16; ++tk) {
        const int slot = ((tk * 4 + fg) ^ (fr & 7)) * 8;
        half8 af[4], bf[4];
#pragma unroll
        for (int mf = 0; mf < 4; ++mf)
          af[mf] = *(const half8*)(xcur + (mf * 16 + fr) * D_DIM + slot);
#pragma unroll
        for (int nf = 0; nf < 4; ++nf)
          bf[nf] = *(const half8*)(wpb + (nf * 16 + tk) * 512);
#pragma unroll
        for (int mf = 0; mf < 4; ++mf)
#pragma unroll
          for (int nf = 0; nf < 4; ++nf)
            acc[mf][nf] = __builtin_amdgcn_mfma_f32_16x16x32_f16(af[mf], bf[nf], acc[mf][nf], 0, 0, 0);
      }
      // ---- epilogue: score partial for this wave's 64 a-cols
      float part[4][4];
#pragma unroll
      for (int mf = 0; mf < 4; ++mf)
#pragma unroll
        for (int r = 0; r < 4; ++r) part[mf][r] = 0.f;
#pragma unroll
      for (int nf = 0; nf < 4; ++nf) {
        const int a_idx = (wv & 3) * 64 + nf * 16 + fr;
        const float wt_a = wt_s[a_idx];
        const float whb_a = whb_s[a_idx];
#pragma unroll
        for (int mf = 0; mf < 4; ++mf)
#pragma unroll
          for (int r = 0; r < 4; ++r)
            part[mf][r] += wt_a * tanh_fast(acc[mf][nf][r] + whb_a);
      }
#pragma unroll
      for (int mask = 1; mask < 16; mask <<= 1)
#pragma unroll
        for (int mf = 0; mf < 4; ++mf)
#pragma unroll
          for (int r = 0; r < 4; ++r) part[mf][r] += __shfl_xor(part[mf][r], mask, 64);
      if (fr == 0) {
#pragma unroll
        for (int mf = 0; mf < 4; ++mf)
#pragma unroll
          for (int r = 0; r < 4; ++r)
            scorep[(wv & 3) * 64 + mf * 16 + fg * 4 + r] = part[mf][r];
      }
    } else if (i + 1 < TPB) {
      // ---- producer: stage tile i+1 into the other buffer
      stage_rows<16>(xnxt, x, t_idx + 1, b, (wv - 4) * 16, lane);
    }
    __syncthreads();   // A: scorep ready (and producer writes done)

    if (tid < BM) {
      float sv = scorep[tid] + scorep[64 + tid] + scorep[128 + tid] + scorep[192 + tid];
      float m = sv;
#pragma unroll
      for (int mask = 1; mask < 64; mask <<= 1) m = fmaxf(m, __shfl_xor(m, mask, 64));
      float p = __expf(sv - m);
      float lsum = p;
#pragma unroll
      for (int mask = 1; mask < 64; mask <<= 1) lsum += __shfl_xor(lsum, mask, 64);
      pbuf[tid] = p;
      if (tid == 0) {
        m_arr[b * NTILES + t_idx] = m;
        l_arr[b * NTILES + t_idx] = lsum;
      }
    }
    __syncthreads();   // B: pbuf ready

    // ---- weighted sum: all 8 waves, 8 rows each, from xcur
    {
      float pacc[8];
#pragma unroll
      for (int j = 0; j < 8; ++j) pacc[j] = 0.f;
#pragma unroll
      for (int r = 0; r < 8; ++r) {
        const int row = wv * 8 + r;
        const float pr = pbuf[row];
        half8 v = *(const half8*)(xcur + row * D_DIM + ((lane ^ (row & 7)) * 8));
#pragma unroll
        for (int j = 0; j < 8; ++j) pacc[j] += pr * (float)v[j];
      }
#pragma unroll
      for (int j = 0; j < 8; ++j) red[wv * 512 + lane * 8 + j] = pacc[j];
    }
    __syncthreads();   // C: red ready (xcur reads complete)

    {
      float s = 0.f;
#pragma unroll
      for (int w2 = 0; w2 < 8; ++w2) s += red[w2 * 512 + tid];
      acc_arr[((size_t)(b * NTILES + t_idx)) * D_DIM + tid] = s;
    }
    __syncthreads();   // D: red consumed; xcur free for producer next iter
  }
}

__global__ void __launch_bounds__(512)
combine_kernel(const float* __restrict__ m_arr, const float* __restrict__ l_arr,
               const float* __restrict__ acc_arr, float* __restrict__ out) {
  __shared__ float ml[NTILES], ls[NTILES], wl[NTILES];
  const int b = blockIdx.x, tid = threadIdx.x;
  if (tid < NTILES) {
    ml[tid] = m_arr[b * NTILES + tid];
    ls[tid] = l_arr[b * NTILES + tid];
  }
  __syncthreads();
  float M = -1e30f;
  for (int i = 0; i < NTILES; ++i) M = fmaxf(M, ml[i]);
  if (tid < NTILES) wl[tid] = __expf(ml[tid] - M);
  __syncthreads();
  float L = 0.f;
  for (int i = 0; i < NTILES; ++i) L += wl[i] * ls[i];
  float sum = 0.f;
  const size_t base = (size_t)b * NTILES * D_DIM + tid;
  for (int i = 0; i < NTILES; ++i) sum += wl[i] * acc_arr[base + (size_t)i * D_DIM];
  out[b * D_DIM + tid] = sum / L;
}

extern "C" void kernel_launch(void* const* d_in, const int* in_sizes, int n_in,
                              void* d_out, int out_size, void* d_ws, size_t ws_size,
                              hipStream_t stream) {
  const float* x = (const float*)d_in[0];
  const float* h = (const float*)d_in[1];
  const float* Wx = (const float*)d_in[2];
  const float* bx = (const float*)d_in[3];
  const float* Wh = (const float*)d_in[4];
  const float* Wt = (const float*)d_in[5];
  // d_in[6] = bt: unused (softmax shift-invariant)

  char* ws = (char*)d_ws;
  _Float16* Wp = (_Float16*)ws;                               // 262144 B (packed)
  float* whb = (float*)(ws + 262144);                         // 65536 B
  float* m_arr = (float*)(ws + 262144 + 65536);               // 32768 B
  float* l_arr = (float*)(ws + 262144 + 65536 + 32768);       // 32768 B
  float* acc_arr = (float*)(ws + 262144 + 65536 + 65536);     // 16.8 MB

  hipFuncSetAttribute(reinterpret_cast<const void*>(paa_main),
                      hipFuncAttributeMaxDynamicSharedMemorySize, SMEM_MAIN);

  hipLaunchKernelGGL(convw_kernel, dim3(64), dim3(256), 0, stream, Wx, Wp);
  hipLaunchKernelGGL(whb_kernel, dim3(B_DIM), dim3(256), 0, stream, h, Wh, bx, whb);
  hipLaunchKernelGGL(paa_main, dim3(NBLK), dim3(512), SMEM_MAIN, stream,
                     x, Wp, whb, Wt, m_arr, l_arr, acc_arr);
  hipLaunchKernelGGL(combine_kernel, dim3(B_DIM), dim3(512), 0, stream,
                     m_arr, l_arr, acc_arr, (float*)d_out);
}

// Round 6
// 465.502 us; speedup vs baseline: 1.4435x; 1.4435x over previous
//
#include <hip/hip_runtime.h>

// PositionAwareAttention: S=8192, B=64, D=512, A=256, all fp32 I/O.
// R6: persistent blocks (256 = 1/CU, 512 thr), W in REGISTERS (128 VGPR/wave,
// loaded once), double-buffered 64-row fp16 x tile, register prefetch of the
// next tile issued before the (LDS+MFMA-only) K-loop -> the prefetch
// issue->consume window crosses no barrier, so plain __syncthreads never
// drains it. 2 barriers/tile. Wave strip = 64 rows x 32 acols.
// k3 combines 128 tile-partials per b. bt omitted (softmax shift-invariant).

#define S_DIM 8192
#define B_DIM 64
#define D_DIM 512
#define A_DIM 256
#define BM 64
#define NTILES 128
#define TPB 32            // tiles per block
#define NBLK 256          // 64 b x 4 sgrp (1 block/CU)

typedef _Float16 half8 __attribute__((ext_vector_type(8)));
typedef float f32x4 __attribute__((ext_vector_type(4)));

// LDS: xs dbuf 2*65536 + red 16384 + scorep 2048 + whb_s 1024 + wt_s 1024
#define SMEM_MAIN (131072 + 16384 + 2048 + 1024 + 1024)

__device__ __forceinline__ float tanh_fast(float x) {
  // tanh(x) = 1 - 2/(exp(2x)+1); exp->inf/0 saturates correctly to +/-1
  float e = __expf(2.0f * x);
  return 1.0f - 2.0f * __builtin_amdgcn_rcpf(e + 1.0f);
}

// Pack Wx (A=256 x K=512 f32) -> fp16 fragment tiles (R4 layout).
// elem (a=ta*16+fr, k=tk*32+fg*8+j) at Wp[(ta*16+tk)*512 + (fg*16+fr)*8 + j]
__global__ void __launch_bounds__(256)
convw_kernel(const float* __restrict__ Wx, _Float16* __restrict__ Wp) {
  const int idx = (blockIdx.x * 256 + threadIdx.x) * 8;
  const int a = idx >> 9;
  const int k = idx & 511;
  f32x4 va = *(const f32x4*)(Wx + idx);
  f32x4 vb = *(const f32x4*)(Wx + idx + 4);
  half8 hx;
#pragma unroll
  for (int i = 0; i < 4; ++i) { hx[i] = (_Float16)va[i]; hx[4 + i] = (_Float16)vb[i]; }
  const int ta = a >> 4, fr = a & 15;
  const int tk = k >> 5, fg = (k >> 3) & 3;
  *(half8*)(Wp + (ta * 16 + tk) * 512 + (fg * 16 + fr) * 8) = hx;
}

__global__ void __launch_bounds__(256)
whb_kernel(const float* __restrict__ h, const float* __restrict__ Wh,
           const float* __restrict__ bx, float* __restrict__ whb) {
  __shared__ float hs[D_DIM];
  const int b = blockIdx.x, tid = threadIdx.x;
  hs[tid] = h[b * D_DIM + tid];
  hs[tid + 256] = h[b * D_DIM + 256 + tid];
  __syncthreads();
  const int g = tid >> 4, i = tid & 15;
  for (int pass = 0; pass < 16; ++pass) {
    const int a = pass * 16 + g;
    const f32x4* wrow = (const f32x4*)(Wh + (size_t)a * D_DIM);
    float dot = 0.f;
#pragma unroll
    for (int k = 0; k < 8; ++k) {
      f32x4 wv = wrow[i + k * 16];
      f32x4 hv = *(const f32x4*)(hs + (i + k * 16) * 4);
      dot += wv[0] * hv[0] + wv[1] * hv[1] + wv[2] * hv[2] + wv[3] * hv[3];
    }
#pragma unroll
    for (int mask = 1; mask < 16; mask <<= 1) dot += __shfl_xor(dot, mask, 64);
    if (i == 0) whb[b * A_DIM + a] = dot + bx[a];
  }
}

__global__ void __launch_bounds__(512, 2)
paa_main(const float* __restrict__ x, const _Float16* __restrict__ Wp,
         const float* __restrict__ whb, const float* __restrict__ Wt,
         float* __restrict__ m_arr, float* __restrict__ l_arr,
         float* __restrict__ acc_arr) {
  extern __shared__ char smem[];
  _Float16* xs0 = (_Float16*)smem;                  // [64][512] f16, 16B-chunk XOR swizzle
  _Float16* xs1 = (_Float16*)(smem + 65536);
  float* red    = (float*)(smem + 131072);          // [8][512]
  float* scorep = (float*)(smem + 131072 + 16384);  // [8][64]
  float* whb_s  = scorep + 512;                     // [256]
  float* wt_s   = whb_s + 256;                      // [256]

  const int tid = threadIdx.x;
  const int lane = tid & 63;
  const int wv = tid >> 6;
  const int b = blockIdx.x >> 2;
  const int sgrp = blockIdx.x & 3;
  const int t0 = sgrp * TPB;

  if (tid < A_DIM) { whb_s[tid] = whb[b * A_DIM + tid]; wt_s[tid] = Wt[tid]; }

  const int fr = lane & 15, fg = lane >> 4;

  // ---- persistent W: wave strip = acols [wv*32, wv*32+32), all K. 128 VGPR.
  half8 wreg[2][16];
#pragma unroll
  for (int nf = 0; nf < 2; ++nf)
#pragma unroll
    for (int tk = 0; tk < 16; ++tk)
      wreg[nf][tk] = *(const half8*)(Wp + ((2 * wv + nf) * 16 + tk) * 512 + lane * 8);

  // ---- prologue: stage tile t0 into xs0 (8 rows per wave; lane = 16B chunk)
  {
    f32x4 va[8], vb[8];
#pragma unroll
    for (int rr = 0; rr < 8; ++rr) {
      const int row = wv * 8 + rr;
      const float* rp = x + ((size_t)(t0 * BM + row) * B_DIM + b) * D_DIM;
      va[rr] = *(const f32x4*)(rp + lane * 8);
      vb[rr] = *(const f32x4*)(rp + lane * 8 + 4);
    }
#pragma unroll
    for (int rr = 0; rr < 8; ++rr) {
      const int row = wv * 8 + rr;
      half8 hx;
#pragma unroll
      for (int j = 0; j < 4; ++j) { hx[j] = (_Float16)va[rr][j]; hx[4 + j] = (_Float16)vb[rr][j]; }
      *(half8*)(xs0 + row * D_DIM + ((lane ^ (row & 7)) * 8)) = hx;
    }
  }
  __syncthreads();

  for (int i = 0; i < TPB; ++i) {
    const int t_idx = t0 + i;
    _Float16* xcur = (i & 1) ? xs1 : xs0;
    _Float16* xnxt = (i & 1) ? xs0 : xs1;
    const bool pf = (i + 1 < TPB);

    // ---- issue prefetch group A (rows wv*8..+3 of tile i+1); stays in flight
    f32x4 pa[4], pb[4];
    if (pf) {
#pragma unroll
      for (int rr = 0; rr < 4; ++rr) {
        const int row = wv * 8 + rr;
        const float* rp = x + ((size_t)((t_idx + 1) * BM + row) * B_DIM + b) * D_DIM;
        pa[rr] = *(const f32x4*)(rp + lane * 8);
        pb[rr] = *(const f32x4*)(rp + lane * 8 + 4);
      }
    }
    __builtin_amdgcn_sched_barrier(0);   // pin: loads issue before K-loop

    // ---- K-loop: LDS + registers only (no vmcnt ops -> prefetch unaffected)
    f32x4 acc[4][2];
#pragma unroll
    for (int mf = 0; mf < 4; ++mf)
#pragma unroll
      for (int nf = 0; nf < 2; ++nf) acc[mf][nf] = (f32x4){0.f, 0.f, 0.f, 0.f};
#pragma unroll
    for (int tk = 0; tk < 16; ++tk) {
      const int slot = ((tk * 4 + fg) ^ (fr & 7)) * 8;
      half8 af[4];
#pragma unroll
      for (int mf = 0; mf < 4; ++mf)
        af[mf] = *(const half8*)(xcur + (mf * 16 + fr) * D_DIM + slot);
#pragma unroll
      for (int mf = 0; mf < 4; ++mf)
#pragma unroll
        for (int nf = 0; nf < 2; ++nf)
          acc[mf][nf] = __builtin_amdgcn_mfma_f32_16x16x32_f16(af[mf], wreg[nf][tk], acc[mf][nf], 0, 0, 0);
    }

    // ---- consume A (HBM latency hidden under K-loop), then issue group B
    if (pf) {
#pragma unroll
      for (int rr = 0; rr < 4; ++rr) {
        const int row = wv * 8 + rr;
        half8 hx;
#pragma unroll
        for (int j = 0; j < 4; ++j) { hx[j] = (_Float16)pa[rr][j]; hx[4 + j] = (_Float16)pb[rr][j]; }
        *(half8*)(xnxt + row * D_DIM + ((lane ^ (row & 7)) * 8)) = hx;
      }
#pragma unroll
      for (int rr = 0; rr < 4; ++rr) {
        const int row = wv * 8 + 4 + rr;
        const float* rp = x + ((size_t)((t_idx + 1) * BM + row) * B_DIM + b) * D_DIM;
        pa[rr] = *(const f32x4*)(rp + lane * 8);
        pb[rr] = *(const f32x4*)(rp + lane * 8 + 4);
      }
    }
    __builtin_amdgcn_sched_barrier(0);

    // ---- epilogue: score partial for this wave's 32 acols
    float part[4][4];
#pragma unroll
    for (int mf = 0; mf < 4; ++mf)
#pragma unroll
      for (int r = 0; r < 4; ++r) part[mf][r] = 0.f;
#pragma unroll
    for (int nf = 0; nf < 2; ++nf) {
      const int a_idx = wv * 32 + nf * 16 + fr;
      const float wt_a = wt_s[a_idx];
      const float whb_a = whb_s[a_idx];
#pragma unroll
      for (int mf = 0; mf < 4; ++mf)
#pragma unroll
        for (int r = 0; r < 4; ++r)
          part[mf][r] += wt_a * tanh_fast(acc[mf][nf][r] + whb_a);
    }
#pragma unroll
    for (int mask = 1; mask < 16; mask <<= 1)
#pragma unroll
      for (int mf = 0; mf < 4; ++mf)
#pragma unroll
        for (int r = 0; r < 4; ++r) part[mf][r] += __shfl_xor(part[mf][r], mask, 64);
    if (fr == 0) {
#pragma unroll
      for (int mf = 0; mf < 4; ++mf)
#pragma unroll
        for (int r = 0; r < 4; ++r)
          scorep[wv * 64 + mf * 16 + fg * 4 + r] = part[mf][r];
    }

    // ---- consume B (hidden under epilogue)
    if (pf) {
#pragma unroll
      for (int rr = 0; rr < 4; ++rr) {
        const int row = wv * 8 + 4 + rr;
        half8 hx;
#pragma unroll
        for (int j = 0; j < 4; ++j) { hx[j] = (_Float16)pa[rr][j]; hx[4 + j] = (_Float16)pb[rr][j]; }
        *(half8*)(xnxt + row * D_DIM + ((lane ^ (row & 7)) * 8)) = hx;
      }
    }

    __syncthreads();   // B1: scorep + xnxt visible (no live prefetch to drain)

    // ---- softmax (all waves compute redundantly; lane = row)
    float sv = 0.f;
#pragma unroll
    for (int w = 0; w < 8; ++w) sv += scorep[w * 64 + lane];
    float m = sv;
#pragma unroll
    for (int mask = 1; mask < 64; mask <<= 1) m = fmaxf(m, __shfl_xor(m, mask, 64));
    float p = __expf(sv - m);
    float lsum = p;
#pragma unroll
    for (int mask = 1; mask < 64; mask <<= 1) lsum += __shfl_xor(lsum, mask, 64);
    if (wv == 0 && lane == 0) {
      m_arr[b * NTILES + t_idx] = m;
      l_arr[b * NTILES + t_idx] = lsum;
    }

    // ---- weighted sum from xcur (each wave: its 8 rows)
    float pacc[8];
#pragma unroll
    for (int j = 0; j < 8; ++j) pacc[j] = 0.f;
#pragma unroll
    for (int r = 0; r < 8; ++r) {
      const int row = wv * 8 + r;
      const float pr = __shfl(p, row, 64);
      half8 v = *(const half8*)(xcur + row * D_DIM + ((lane ^ (row & 7)) * 8));
#pragma unroll
      for (int j = 0; j < 8; ++j) pacc[j] += pr * (float)v[j];
    }
    *(f32x4*)(red + wv * 512 + lane * 8) = (f32x4){pacc[0], pacc[1], pacc[2], pacc[3]};
    *(f32x4*)(red + wv * 512 + lane * 8 + 4) = (f32x4){pacc[4], pacc[5], pacc[6], pacc[7]};

    __syncthreads();   // B2: red ready; also guards dbuf reuse next iter

    float s = 0.f;
#pragma unroll
    for (int w2 = 0; w2 < 8; ++w2) s += red[w2 * 512 + tid];
    acc_arr[((size_t)(b * NTILES + t_idx)) * D_DIM + tid] = s;
  }
}

__global__ void __launch_bounds__(512)
combine_kernel(const float* __restrict__ m_arr, const float* __restrict__ l_arr,
               const float* __restrict__ acc_arr, float* __restrict__ out) {
  __shared__ float ml[NTILES], ls[NTILES], wl[NTILES];
  const int b = blockIdx.x, tid = threadIdx.x;
  if (tid < NTILES) {
    ml[tid] = m_arr[b * NTILES + tid];
    ls[tid] = l_arr[b * NTILES + tid];
  }
  __syncthreads();
  float M = -1e30f;
  for (int i = 0; i < NTILES; ++i) M = fmaxf(M, ml[i]);
  if (tid < NTILES) wl[tid] = __expf(ml[tid] - M);
  __syncthreads();
  float L = 0.f;
  for (int i = 0; i < NTILES; ++i) L += wl[i] * ls[i];
  float sum = 0.f;
  const size_t base = (size_t)b * NTILES * D_DIM + tid;
  for (int i = 0; i < NTILES; ++i) sum += wl[i] * acc_arr[base + (size_t)i * D_DIM];
  out[b * D_DIM + tid] = sum / L;
}

extern "C" void kernel_launch(void* const* d_in, const int* in_sizes, int n_in,
                              void* d_out, int out_size, void* d_ws, size_t ws_size,
                              hipStream_t stream) {
  const float* x = (const float*)d_in[0];
  const float* h = (const float*)d_in[1];
  const float* Wx = (const float*)d_in[2];
  const float* bx = (const float*)d_in[3];
  const float* Wh = (const float*)d_in[4];
  const float* Wt = (const float*)d_in[5];
  // d_in[6] = bt: unused (softmax shift-invariant)

  char* ws = (char*)d_ws;
  _Float16* Wp = (_Float16*)ws;                               // 262144 B (packed)
  float* whb = (float*)(ws + 262144);                         // 65536 B
  float* m_arr = (float*)(ws + 262144 + 65536);               // 32768 B
  float* l_arr = (float*)(ws + 262144 + 65536 + 32768);       // 32768 B
  float* acc_arr = (float*)(ws + 262144 + 65536 + 65536);     // 16.8 MB

  hipFuncSetAttribute(reinterpret_cast<const void*>(paa_main),
                      hipFuncAttributeMaxDynamicSharedMemorySize, SMEM_MAIN);

  hipLaunchKernelGGL(convw_kernel, dim3(64), dim3(256), 0, stream, Wx, Wp);
  hipLaunchKernelGGL(whb_kernel, dim3(B_DIM), dim3(256), 0, stream, h, Wh, bx, whb);
  hipLaunchKernelGGL(paa_main, dim3(NBLK), dim3(512), SMEM_MAIN, stream,
                     x, Wp, whb, Wt, m_arr, l_arr, acc_arr);
  hipLaunchKernelGGL(combine_kernel, dim3(B_DIM), dim3(512), 0, stream,
                     m_arr, l_arr, acc_arr, (float*)d_out);
}